// Round 1
// baseline (459.566 us; speedup 1.0000x reference)
//
#include <hip/hip_runtime.h>
#include <hip/hip_bf16.h>

#define BATCH 4096
#define TSTEPS 256
#define NF 5
#define H 64
#define BT 16          // batch tile per block
#define LDH 136        // hreg row stride in ushorts (pad: 2-way max on b128 reads)
#define NBLK (BATCH / BT)

typedef __attribute__((ext_vector_type(8))) short bf16x8;
typedef __attribute__((ext_vector_type(4))) float f32x4;

__device__ __forceinline__ ushort f2bf(float f) {
    union { float f; unsigned u; } v; v.f = f;
    unsigned u = v.u;
    unsigned r = (u + 0x7FFFu + ((u >> 16) & 1u)) >> 16;  // RNE
    return (ushort)r;
}
__device__ __forceinline__ float sigm(float x) { return 1.0f / (1.0f + __expf(-x)); }
__device__ __forceinline__ float tanhx(float x) { return 1.0f - 2.0f / (__expf(2.0f * x) + 1.0f); }

__global__ __launch_bounds__(256, 1)
void lstm2_kernel(const float* __restrict__ x,
                  const float* __restrict__ Wih0, const float* __restrict__ Whh0,
                  const float* __restrict__ bih0, const float* __restrict__ bhh0,
                  const float* __restrict__ Wih1, const float* __restrict__ Whh1,
                  const float* __restrict__ bih1, const float* __restrict__ bhh1,
                  const float* __restrict__ Wfc, const float* __restrict__ bfc,
                  float* __restrict__ out)
{
    __shared__ union {
        ushort xs[TSTEPS * BT * 8];   // bf16 x staged [t][b][8] (f padded 5..7 = 0)
        float  hfin[BT * H];          // reused in epilogue for fp32 h1 final
    } uS;
    __shared__ ushort hreg[BT * LDH]; // bf16 state: cols 0..63 = h0, 64..127 = h1

    const int tid = threadIdx.x;
    const int w   = tid >> 6;    // wave 0..3
    const int l   = tid & 63;
    const int g   = l >> 4;      // k-group 0..3
    const int lr  = l & 15;      // row (A) / col (B,D) index
    const int bb  = blockIdx.x * BT;

    // ---- stage x tile into LDS as bf16 ----
    {
        const int b  = tid & 15;
        const int t0 = tid >> 4;
        for (int tt = t0; tt < TSTEPS; tt += 16) {
            const float* xp = x + ((size_t)(bb + b) * TSTEPS + tt) * NF;
            bf16x8 v;
            v[0] = (short)f2bf(xp[0]); v[1] = (short)f2bf(xp[1]);
            v[2] = (short)f2bf(xp[2]); v[3] = (short)f2bf(xp[3]);
            v[4] = (short)f2bf(xp[4]); v[5] = 0; v[6] = 0; v[7] = 0;
            *(bf16x8*)&uS.xs[(tt * BT + b) * 8] = v;
        }
    }
    for (int i = tid; i < BT * LDH; i += 256) hreg[i] = 0;

    // ---- weight fragments resident in VGPRs ----
    // wave w covers unit u = 16w+lr; gate gi lives at col n = 64*gi + u.
    // k-map (both A and B): chunk c, group g, elem j -> k = 32c + 8g + j.
    const int u = 16 * w + lr;
    bf16x8 w0f[4][3], w1f[4][4];
    float b0v[4], b1v[4];
    #pragma unroll
    for (int gi = 0; gi < 4; ++gi) {
        const int n = 64 * gi + u;
        b0v[gi] = bih0[n] + bhh0[n];
        b1v[gi] = bih1[n] + bhh1[n];
        #pragma unroll
        for (int c = 0; c < 2; ++c) {                  // layer0 recurrent: Whh0[n][k]
            const float* p = Whh0 + n * H + 32 * c + 8 * g;
            bf16x8 v;
            #pragma unroll
            for (int j = 0; j < 8; ++j) v[j] = (short)f2bf(p[j]);
            w0f[gi][c] = v;
        }
        {                                              // layer0 x-chunk: Wih0[n][8g+j], pad 0
            bf16x8 v;
            #pragma unroll
            for (int j = 0; j < 8; ++j) {
                int kk = 8 * g + j;
                v[j] = (kk < NF) ? (short)f2bf(Wih0[n * NF + kk]) : (short)0;
            }
            w0f[gi][2] = v;
        }
        #pragma unroll
        for (int c = 0; c < 4; ++c) {                  // layer1: [Wih1 | Whh1]
            const float* p = (c < 2) ? (Wih1 + n * H + 32 * c + 8 * g)
                                     : (Whh1 + n * H + 32 * (c - 2) + 8 * g);
            bf16x8 v;
            #pragma unroll
            for (int j = 0; j < 8; ++j) v[j] = (short)f2bf(p[j]);
            w1f[gi][c] = v;
        }
    }

    float c0[4] = {0, 0, 0, 0}, c1[4] = {0, 0, 0, 0};
    float h1fin[4] = {0, 0, 0, 0};

    __syncthreads();

    const int arow = lr * LDH;

    #pragma unroll 1
    for (int t = 0; t < TSTEPS; ++t) {
        // phase 1: A fragments (h0 old, h1 old, x_t)
        bf16x8 a00 = *(const bf16x8*)&hreg[arow + 8 * g];
        bf16x8 a01 = *(const bf16x8*)&hreg[arow + 32 + 8 * g];
        bf16x8 a12 = *(const bf16x8*)&hreg[arow + 64 + 8 * g];
        bf16x8 a13 = *(const bf16x8*)&hreg[arow + 96 + 8 * g];
        bf16x8 ax = {0, 0, 0, 0, 0, 0, 0, 0};
        if (g == 0) ax = *(const bf16x8*)&uS.xs[(t * BT + lr) * 8];

        // phase 2: layer0 MFMAs (acc init = bias, broadcast over rows)
        f32x4 acc[4];
        #pragma unroll
        for (int gi = 0; gi < 4; ++gi) { f32x4 a = {b0v[gi], b0v[gi], b0v[gi], b0v[gi]}; acc[gi] = a; }
        #pragma unroll
        for (int gi = 0; gi < 4; ++gi) acc[gi] = __builtin_amdgcn_mfma_f32_16x16x32_bf16(a00, w0f[gi][0], acc[gi], 0, 0, 0);
        #pragma unroll
        for (int gi = 0; gi < 4; ++gi) acc[gi] = __builtin_amdgcn_mfma_f32_16x16x32_bf16(a01, w0f[gi][1], acc[gi], 0, 0, 0);
        #pragma unroll
        for (int gi = 0; gi < 4; ++gi) acc[gi] = __builtin_amdgcn_mfma_f32_16x16x32_bf16(ax, w0f[gi][2], acc[gi], 0, 0, 0);

        __syncthreads();   // all waves done reading old h0

        // phase 4: layer0 elementwise, write h0new (bf16)
        #pragma unroll
        for (int r = 0; r < 4; ++r) {
            float iv = sigm(acc[0][r]);
            float fv = sigm(acc[1][r]);
            float gv = tanhx(acc[2][r]);
            float ov = sigm(acc[3][r]);
            float cc = fv * c0[r] + iv * gv;
            c0[r] = cc;
            float hh = ov * tanhx(cc);
            hreg[(4 * g + r) * LDH + u] = f2bf(hh);
        }
        __syncthreads();   // h0new visible

        // phase 6: layer1 MFMAs ([h0new | h1old], K=128)
        bf16x8 a10 = *(const bf16x8*)&hreg[arow + 8 * g];
        bf16x8 a11 = *(const bf16x8*)&hreg[arow + 32 + 8 * g];
        #pragma unroll
        for (int gi = 0; gi < 4; ++gi) { f32x4 a = {b1v[gi], b1v[gi], b1v[gi], b1v[gi]}; acc[gi] = a; }
        #pragma unroll
        for (int gi = 0; gi < 4; ++gi) acc[gi] = __builtin_amdgcn_mfma_f32_16x16x32_bf16(a10, w1f[gi][0], acc[gi], 0, 0, 0);
        #pragma unroll
        for (int gi = 0; gi < 4; ++gi) acc[gi] = __builtin_amdgcn_mfma_f32_16x16x32_bf16(a11, w1f[gi][1], acc[gi], 0, 0, 0);
        #pragma unroll
        for (int gi = 0; gi < 4; ++gi) acc[gi] = __builtin_amdgcn_mfma_f32_16x16x32_bf16(a12, w1f[gi][2], acc[gi], 0, 0, 0);
        #pragma unroll
        for (int gi = 0; gi < 4; ++gi) acc[gi] = __builtin_amdgcn_mfma_f32_16x16x32_bf16(a13, w1f[gi][3], acc[gi], 0, 0, 0);

        // layer1 elementwise, write h1new
        #pragma unroll
        for (int r = 0; r < 4; ++r) {
            float iv = sigm(acc[0][r]);
            float fv = sigm(acc[1][r]);
            float gv = tanhx(acc[2][r]);
            float ov = sigm(acc[3][r]);
            float cc = fv * c1[r] + iv * gv;
            c1[r] = cc;
            float hh = ov * tanhx(cc);
            h1fin[r] = hh;
            hreg[(4 * g + r) * LDH + 64 + u] = f2bf(hh);
        }
        __syncthreads();   // h1new visible before next step
    }

    // epilogue: FC on fp32 final h1
    #pragma unroll
    for (int r = 0; r < 4; ++r) uS.hfin[(4 * g + r) * H + u] = h1fin[r];
    __syncthreads();
    if (tid < BT * 2) {
        const int b = tid >> 1, cls = tid & 1;
        float s = bfc[cls];
        for (int k = 0; k < H; ++k) s += uS.hfin[b * H + k] * Wfc[cls * H + k];
        out[(size_t)(bb + b) * 2 + cls] = s;
    }
}

extern "C" void kernel_launch(void* const* d_in, const int* in_sizes, int n_in,
                              void* d_out, int out_size, void* d_ws, size_t ws_size,
                              hipStream_t stream) {
    const float* x    = (const float*)d_in[0];
    const float* Wih0 = (const float*)d_in[1];
    const float* Whh0 = (const float*)d_in[2];
    const float* bih0 = (const float*)d_in[3];
    const float* bhh0 = (const float*)d_in[4];
    const float* Wih1 = (const float*)d_in[5];
    const float* Whh1 = (const float*)d_in[6];
    const float* bih1 = (const float*)d_in[7];
    const float* bhh1 = (const float*)d_in[8];
    const float* Wfc  = (const float*)d_in[9];
    const float* bfc  = (const float*)d_in[10];
    float* out = (float*)d_out;

    lstm2_kernel<<<NBLK, 256, 0, stream>>>(x, Wih0, Whh0, bih0, bhh0,
                                           Wih1, Whh1, bih1, bhh1, Wfc, bfc, out);
}

// Round 2
// 255.604 us; speedup vs baseline: 1.7980x; 1.7980x over previous
//
#include <hip/hip_runtime.h>
#include <hip/hip_bf16.h>

#define BATCH 4096
#define TSTEPS 256
#define NF 5
#define H 64
#define BT 16          // batch tile per block
#define LDH 136        // hreg row stride in ushorts
#define NBLK (BATCH / BT)

typedef __attribute__((ext_vector_type(8))) short bf16x8;
typedef __attribute__((ext_vector_type(4))) float f32x4;

__device__ __forceinline__ ushort f2bf(float f) {
    union { float f; unsigned u; } v; v.f = f;
    unsigned u = v.u;
    unsigned r = (u + 0x7FFFu + ((u >> 16) & 1u)) >> 16;  // RNE
    return (ushort)r;
}
// fast activations: v_exp_f32 + v_rcp_f32 (approx, ~2ulp — far below bf16 noise)
__device__ __forceinline__ float sigm(float x) {
    return __builtin_amdgcn_rcpf(1.0f + __expf(-x));
}
__device__ __forceinline__ float tanhx(float x) {
    return 1.0f - 2.0f * __builtin_amdgcn_rcpf(1.0f + __expf(2.0f * x));
}

__global__ __launch_bounds__(256, 1)
void lstm2_kernel(const float* __restrict__ x,
                  const float* __restrict__ Wih0, const float* __restrict__ Whh0,
                  const float* __restrict__ bih0, const float* __restrict__ bhh0,
                  const float* __restrict__ Wih1, const float* __restrict__ Whh1,
                  const float* __restrict__ bih1, const float* __restrict__ bhh1,
                  const float* __restrict__ Wfc, const float* __restrict__ bfc,
                  float* __restrict__ out)
{
    __shared__ union {
        ushort xs[TSTEPS * BT * 8];   // bf16 x staged [t][b][8] (f padded 5..7 = 0)
        float  hfin[BT * H];          // epilogue: fp32 final h1
    } uS;
    // double-buffered bf16 state: cols 0..63 = h0, 64..127 = h1
    __shared__ ushort hreg[2][BT * LDH];

    const int tid = threadIdx.x;
    const int w   = tid >> 6;    // wave 0..3
    const int l   = tid & 63;
    const int g   = l >> 4;      // k-group 0..3
    const int lr  = l & 15;      // row (A) / col (B,D) index
    const int bb  = blockIdx.x * BT;

    // ---- stage x tile into LDS as bf16 ----
    {
        const int b  = tid & 15;
        const int t0 = tid >> 4;
        for (int tt = t0; tt < TSTEPS; tt += 16) {
            const float* xp = x + ((size_t)(bb + b) * TSTEPS + tt) * NF;
            bf16x8 v;
            v[0] = (short)f2bf(xp[0]); v[1] = (short)f2bf(xp[1]);
            v[2] = (short)f2bf(xp[2]); v[3] = (short)f2bf(xp[3]);
            v[4] = (short)f2bf(xp[4]); v[5] = 0; v[6] = 0; v[7] = 0;
            *(bf16x8*)&uS.xs[(tt * BT + b) * 8] = v;
        }
    }
    for (int i = tid; i < 2 * BT * LDH; i += 256) hreg[0][i] = 0;

    // ---- weight fragments resident in VGPRs ----
    // wave w covers unit u = 16w+lr; gate gi lives at col n = 64*gi + u.
    // k-map (both A and B): chunk c, group g, elem j -> k = 32c + 8g + j.
    const int u = 16 * w + lr;
    bf16x8 w0f[4][3], w1f[4][4];
    float b0v[4], b1v[4];
    #pragma unroll
    for (int gi = 0; gi < 4; ++gi) {
        const int n = 64 * gi + u;
        b0v[gi] = bih0[n] + bhh0[n];
        b1v[gi] = bih1[n] + bhh1[n];
        #pragma unroll
        for (int c = 0; c < 2; ++c) {                  // layer0 recurrent: Whh0[n][k]
            const float* p = Whh0 + n * H + 32 * c + 8 * g;
            bf16x8 v;
            #pragma unroll
            for (int j = 0; j < 8; ++j) v[j] = (short)f2bf(p[j]);
            w0f[gi][c] = v;
        }
        {                                              // layer0 x-chunk: Wih0[n][8g+j], pad 0
            bf16x8 v;
            #pragma unroll
            for (int j = 0; j < 8; ++j) {
                int kk = 8 * g + j;
                v[j] = (kk < NF) ? (short)f2bf(Wih0[n * NF + kk]) : (short)0;
            }
            w0f[gi][2] = v;
        }
        #pragma unroll
        for (int c = 0; c < 4; ++c) {                  // layer1: [Wih1 | Whh1]
            const float* p = (c < 2) ? (Wih1 + n * H + 32 * c + 8 * g)
                                     : (Whh1 + n * H + 32 * (c - 2) + 8 * g);
            bf16x8 v;
            #pragma unroll
            for (int j = 0; j < 8; ++j) v[j] = (short)f2bf(p[j]);
            w1f[gi][c] = v;
        }
    }

    float c0[4] = {0, 0, 0, 0}, c1[4] = {0, 0, 0, 0};
    float h1fin[4] = {0, 0, 0, 0};

    __syncthreads();

    const int arow = lr * LDH;

    // Software-pipelined: iteration t does layer0 step t (reads h0[t-1], x[t])
    // and layer1 step t-1 (reads h0[t-1], h1[t-2]) — no intra-iteration dep.
    // Double-buffered hreg -> ONE barrier per iteration.
    auto body = [&](int t, const ushort* __restrict__ rb, ushort* __restrict__ wb) {
        const bool do0 = (t < TSTEPS);
        const bool do1 = (t >= 1);

        bf16x8 a00 = *(const bf16x8*)&rb[arow + 8 * g];        // h0 chunk 0
        bf16x8 a01 = *(const bf16x8*)&rb[arow + 32 + 8 * g];   // h0 chunk 1
        bf16x8 a12, a13;
        if (do1) {
            a12 = *(const bf16x8*)&rb[arow + 64 + 8 * g];      // h1 chunk 0
            a13 = *(const bf16x8*)&rb[arow + 96 + 8 * g];      // h1 chunk 1
        }
        bf16x8 ax = {0, 0, 0, 0, 0, 0, 0, 0};
        if (do0 && g == 0) ax = *(const bf16x8*)&uS.xs[(t * BT + lr) * 8];

        f32x4 acc0[4], acc1[4];
        if (do0) {
            #pragma unroll
            for (int gi = 0; gi < 4; ++gi) { f32x4 a = {b0v[gi], b0v[gi], b0v[gi], b0v[gi]}; acc0[gi] = a; }
            #pragma unroll
            for (int gi = 0; gi < 4; ++gi) acc0[gi] = __builtin_amdgcn_mfma_f32_16x16x32_bf16(a00, w0f[gi][0], acc0[gi], 0, 0, 0);
            #pragma unroll
            for (int gi = 0; gi < 4; ++gi) acc0[gi] = __builtin_amdgcn_mfma_f32_16x16x32_bf16(a01, w0f[gi][1], acc0[gi], 0, 0, 0);
            #pragma unroll
            for (int gi = 0; gi < 4; ++gi) acc0[gi] = __builtin_amdgcn_mfma_f32_16x16x32_bf16(ax,  w0f[gi][2], acc0[gi], 0, 0, 0);
        }
        if (do1) {
            #pragma unroll
            for (int gi = 0; gi < 4; ++gi) { f32x4 a = {b1v[gi], b1v[gi], b1v[gi], b1v[gi]}; acc1[gi] = a; }
            #pragma unroll
            for (int gi = 0; gi < 4; ++gi) acc1[gi] = __builtin_amdgcn_mfma_f32_16x16x32_bf16(a00, w1f[gi][0], acc1[gi], 0, 0, 0);
            #pragma unroll
            for (int gi = 0; gi < 4; ++gi) acc1[gi] = __builtin_amdgcn_mfma_f32_16x16x32_bf16(a01, w1f[gi][1], acc1[gi], 0, 0, 0);
            #pragma unroll
            for (int gi = 0; gi < 4; ++gi) acc1[gi] = __builtin_amdgcn_mfma_f32_16x16x32_bf16(a12, w1f[gi][2], acc1[gi], 0, 0, 0);
            #pragma unroll
            for (int gi = 0; gi < 4; ++gi) acc1[gi] = __builtin_amdgcn_mfma_f32_16x16x32_bf16(a13, w1f[gi][3], acc1[gi], 0, 0, 0);
        }

        if (do0) {
            #pragma unroll
            for (int r = 0; r < 4; ++r) {
                float iv = sigm(acc0[0][r]);
                float fv = sigm(acc0[1][r]);
                float gv = tanhx(acc0[2][r]);
                float ov = sigm(acc0[3][r]);
                float cc = fv * c0[r] + iv * gv;
                c0[r] = cc;
                float hh = ov * tanhx(cc);
                wb[(4 * g + r) * LDH + u] = f2bf(hh);
            }
        }
        if (do1) {
            #pragma unroll
            for (int r = 0; r < 4; ++r) {
                float iv = sigm(acc1[0][r]);
                float fv = sigm(acc1[1][r]);
                float gv = tanhx(acc1[2][r]);
                float ov = sigm(acc1[3][r]);
                float cc = fv * c1[r] + iv * gv;
                c1[r] = cc;
                float hh = ov * tanhx(cc);
                h1fin[r] = hh;
                wb[(4 * g + r) * LDH + 64 + u] = f2bf(hh);
            }
        }
        __syncthreads();
    };

    #pragma unroll 1
    for (int t = 0; t < TSTEPS; t += 2) {
        body(t,     hreg[0], hreg[1]);
        body(t + 1, hreg[1], hreg[0]);
    }
    body(TSTEPS, hreg[0], hreg[1]);   // drain: layer1 step T-1

    // epilogue: FC on fp32 final h1
    #pragma unroll
    for (int r = 0; r < 4; ++r) uS.hfin[(4 * g + r) * H + u] = h1fin[r];
    __syncthreads();
    if (tid < BT * 2) {
        const int b = tid >> 1, cls = tid & 1;
        float s = bfc[cls];
        for (int k = 0; k < H; ++k) s += uS.hfin[b * H + k] * Wfc[cls * H + k];
        out[(size_t)(bb + b) * 2 + cls] = s;
    }
}

extern "C" void kernel_launch(void* const* d_in, const int* in_sizes, int n_in,
                              void* d_out, int out_size, void* d_ws, size_t ws_size,
                              hipStream_t stream) {
    const float* x    = (const float*)d_in[0];
    const float* Wih0 = (const float*)d_in[1];
    const float* Whh0 = (const float*)d_in[2];
    const float* bih0 = (const float*)d_in[3];
    const float* bhh0 = (const float*)d_in[4];
    const float* Wih1 = (const float*)d_in[5];
    const float* Whh1 = (const float*)d_in[6];
    const float* bih1 = (const float*)d_in[7];
    const float* bhh1 = (const float*)d_in[8];
    const float* Wfc  = (const float*)d_in[9];
    const float* bfc  = (const float*)d_in[10];
    float* out = (float*)d_out;

    lstm2_kernel<<<NBLK, 256, 0, stream>>>(x, Wih0, Whh0, bih0, bhh0,
                                           Wih1, Whh1, bih1, bhh1, Wfc, bfc, out);
}

// Round 3
// 248.153 us; speedup vs baseline: 1.8519x; 1.0300x over previous
//
#include <hip/hip_runtime.h>
#include <hip/hip_bf16.h>

#define BATCH 4096
#define TSTEPS 256
#define NF 5
#define H 64
#define BT 8           // batch tile per block (sparse rows 0,1,4,5,8,9,12,13)
#define LDH 136        // hreg row stride in ushorts (272B = 17*16B, b128-aligned)
#define NBLK (BATCH / BT)   // 512 blocks -> 2 blocks/CU -> 2 waves/SIMD

typedef __attribute__((ext_vector_type(8))) short bf16x8;
typedef __attribute__((ext_vector_type(4))) float f32x4;

#define LOG2E 1.4426950408889634f
#define TWOLOG2E 2.8853900817779268f

__device__ __forceinline__ ushort f2bf(float f) {
    union { float f; unsigned u; } v; v.f = f;
    unsigned u = v.u;
    unsigned r = (u + 0x7FFFu + ((u >> 16) & 1u)) >> 16;  // RNE
    return (ushort)r;
}
__device__ __forceinline__ float bf2f(ushort s) {
    union { unsigned u; float f; } v; v.u = ((unsigned)s) << 16;
    return v.f;
}
// preacts are PRE-SCALED in the weights: sigm rows by -log2e, tanh rows by +2log2e
__device__ __forceinline__ float sigm_s(float s) {           // s = -x*log2e
    return __builtin_amdgcn_rcpf(1.0f + __builtin_amdgcn_exp2f(s));
}
__device__ __forceinline__ float tanh_s(float s) {           // s = 2x*log2e
    return 1.0f - 2.0f * __builtin_amdgcn_rcpf(1.0f + __builtin_amdgcn_exp2f(s));
}

__global__ __launch_bounds__(256, 2)
void lstm2_kernel(const float* __restrict__ x,
                  const float* __restrict__ Wih0, const float* __restrict__ Whh0,
                  const float* __restrict__ bih0, const float* __restrict__ bhh0,
                  const float* __restrict__ Wih1, const float* __restrict__ Whh1,
                  const float* __restrict__ bih1, const float* __restrict__ bhh1,
                  const float* __restrict__ Wfc, const float* __restrict__ bfc,
                  float* __restrict__ out)
{
    __shared__ union {
        ushort xs[TSTEPS * BT * 8];   // bf16 x staged [t][b][8]; cols 5,6 = 1.0 (bias), 7 = 0
        float  hfin[BT * H];          // epilogue: fp32 final h1
    } uS;
    // double-buffered bf16 state rows 0..15 (sparse: rows 2,3,6,7,10,11,14,15 stay 0)
    __shared__ ushort hreg[2][16 * LDH];

    const int tid = threadIdx.x;
    const int w   = tid >> 6;    // wave 0..3
    const int l   = tid & 63;
    const int g   = l >> 4;      // k-group / D-row group
    const int lr  = l & 15;      // A row / B,D col index
    const int bb  = blockIdx.x * BT;

    // ---- stage x tile into LDS as bf16; pad cols 5,6 = 1.0 for bias columns ----
    {
        const int b  = tid & 7;
        const int t0 = tid >> 3;
        const ushort one = f2bf(1.0f);
        for (int tt = t0; tt < TSTEPS; tt += 32) {
            const float* xp = x + ((size_t)(bb + b) * TSTEPS + tt) * NF;
            bf16x8 v;
            v[0] = (short)f2bf(xp[0]); v[1] = (short)f2bf(xp[1]);
            v[2] = (short)f2bf(xp[2]); v[3] = (short)f2bf(xp[3]);
            v[4] = (short)f2bf(xp[4]); v[5] = (short)one; v[6] = (short)one; v[7] = 0;
            *(bf16x8*)&uS.xs[(tt * BT + b) * 8] = v;
        }
    }
    for (int i = tid; i < 2 * 16 * LDH; i += 256) hreg[0][i] = 0;

    // ---- weight fragments resident in VGPRs, gate-scaled ----
    // wave w covers unit u = 16w+lr; gate gi at col n = 64*gi + u.
    // scale: sigm gates (i,f,o) -> -log2e ; tanh gate (g, gi==2) -> +2log2e
    // k-map (A and B): chunk c, group g, elem j -> k = 32c + 8g + j.
    const int u = 16 * w + lr;
    bf16x8 w0f[4][3], w1f[4][4];
    float b1v[4];
    #pragma unroll
    for (int gi = 0; gi < 4; ++gi) {
        const float sc = (gi == 2) ? TWOLOG2E : -LOG2E;
        const int n = 64 * gi + u;
        const float b0 = (bih0[n] + bhh0[n]) * sc;
        b1v[gi] = (bih1[n] + bhh1[n]) * sc;
        #pragma unroll
        for (int c = 0; c < 2; ++c) {                  // layer0 recurrent: Whh0[n][k]
            const float* p = Whh0 + n * H + 32 * c + 8 * g;
            bf16x8 v;
            #pragma unroll
            for (int j = 0; j < 8; ++j) v[j] = (short)f2bf(p[j] * sc);
            w0f[gi][c] = v;
        }
        {   // layer0 x-chunk: cols 0..4 = Wih0 scaled; col5 = bias_hi, col6 = bias_lo
            const ushort bhi = f2bf(b0);
            const ushort blo = f2bf(b0 - bf2f(bhi));
            bf16x8 v;
            #pragma unroll
            for (int j = 0; j < 8; ++j) {
                int kk = 8 * g + j;
                ushort val = 0;
                if (kk < NF) val = f2bf(Wih0[n * NF + kk] * sc);
                else if (kk == 5) val = bhi;
                else if (kk == 6) val = blo;
                v[j] = (short)val;
            }
            w0f[gi][2] = v;
        }
        #pragma unroll
        for (int c = 0; c < 4; ++c) {                  // layer1: [Wih1 | Whh1]
            const float* p = (c < 2) ? (Wih1 + n * H + 32 * c + 8 * g)
                                     : (Whh1 + n * H + 32 * (c - 2) + 8 * g);
            bf16x8 v;
            #pragma unroll
            for (int j = 0; j < 8; ++j) v[j] = (short)f2bf(p[j] * sc);
            w1f[gi][c] = v;
        }
    }

    // lane group g owns batches {2g, 2g+1} (rows 4g+0, 4g+1)
    float c0[2] = {0, 0}, c1[2] = {0, 0};
    float h1fin[2] = {0, 0};
    const bool xlane = (g == 0) && ((lr & 2) == 0);
    const int  bx    = ((lr >> 2) << 1) | (lr & 1);    // batch with rho(b)==lr

    __syncthreads();

    const int arow = lr * LDH;

    // Pipelined: iteration t does layer0 step t (h0[t-1], x[t]) and layer1 step
    // t-1 (h0[t-1], h1[t-2]). Double-buffered hreg -> ONE barrier per iteration.
    auto body = [&](int t, const ushort* __restrict__ rb, ushort* __restrict__ wb) {
        const bool do0 = (t < TSTEPS);
        const bool do1 = (t >= 1);

        bf16x8 a00 = *(const bf16x8*)&rb[arow + 8 * g];        // h0 chunk 0
        bf16x8 a01 = *(const bf16x8*)&rb[arow + 32 + 8 * g];   // h0 chunk 1
        bf16x8 a12, a13;
        if (do1) {
            a12 = *(const bf16x8*)&rb[arow + 64 + 8 * g];      // h1 chunk 0
            a13 = *(const bf16x8*)&rb[arow + 96 + 8 * g];      // h1 chunk 1
        }
        bf16x8 ax = {0, 0, 0, 0, 0, 0, 0, 0};
        if (do0 && xlane) ax = *(const bf16x8*)&uS.xs[(t * BT + bx) * 8];

        f32x4 acc0[4], acc1[4];
        if (do0) {
            #pragma unroll
            for (int gi = 0; gi < 4; ++gi) { f32x4 z = {0, 0, 0, 0}; acc0[gi] = z; }
            #pragma unroll
            for (int gi = 0; gi < 4; ++gi) acc0[gi] = __builtin_amdgcn_mfma_f32_16x16x32_bf16(a00, w0f[gi][0], acc0[gi], 0, 0, 0);
            #pragma unroll
            for (int gi = 0; gi < 4; ++gi) acc0[gi] = __builtin_amdgcn_mfma_f32_16x16x32_bf16(a01, w0f[gi][1], acc0[gi], 0, 0, 0);
            #pragma unroll
            for (int gi = 0; gi < 4; ++gi) acc0[gi] = __builtin_amdgcn_mfma_f32_16x16x32_bf16(ax,  w0f[gi][2], acc0[gi], 0, 0, 0);
        }
        if (do1) {
            #pragma unroll
            for (int gi = 0; gi < 4; ++gi) { f32x4 a = {b1v[gi], b1v[gi], b1v[gi], b1v[gi]}; acc1[gi] = a; }
            #pragma unroll
            for (int gi = 0; gi < 4; ++gi) acc1[gi] = __builtin_amdgcn_mfma_f32_16x16x32_bf16(a00, w1f[gi][0], acc1[gi], 0, 0, 0);
            #pragma unroll
            for (int gi = 0; gi < 4; ++gi) acc1[gi] = __builtin_amdgcn_mfma_f32_16x16x32_bf16(a01, w1f[gi][1], acc1[gi], 0, 0, 0);
            #pragma unroll
            for (int gi = 0; gi < 4; ++gi) acc1[gi] = __builtin_amdgcn_mfma_f32_16x16x32_bf16(a12, w1f[gi][2], acc1[gi], 0, 0, 0);
            #pragma unroll
            for (int gi = 0; gi < 4; ++gi) acc1[gi] = __builtin_amdgcn_mfma_f32_16x16x32_bf16(a13, w1f[gi][3], acc1[gi], 0, 0, 0);
        }

        if (do0) {
            #pragma unroll
            for (int r = 0; r < 2; ++r) {              // rows 4g+r, batches 2g+r
                float iv = sigm_s(acc0[0][r]);
                float fv = sigm_s(acc0[1][r]);
                float gv = tanh_s(acc0[2][r]);
                float ov = sigm_s(acc0[3][r]);
                float cc = fv * c0[r] + iv * gv;
                c0[r] = cc;
                float hh = ov * tanh_s(cc * TWOLOG2E);
                wb[(4 * g + r) * LDH + u] = f2bf(hh);
            }
        }
        if (do1) {
            #pragma unroll
            for (int r = 0; r < 2; ++r) {
                float iv = sigm_s(acc1[0][r]);
                float fv = sigm_s(acc1[1][r]);
                float gv = tanh_s(acc1[2][r]);
                float ov = sigm_s(acc1[3][r]);
                float cc = fv * c1[r] + iv * gv;
                c1[r] = cc;
                float hh = ov * tanh_s(cc * TWOLOG2E);
                h1fin[r] = hh;
                wb[(4 * g + r) * LDH + 64 + u] = f2bf(hh);
            }
        }
        __syncthreads();
    };

    #pragma unroll 1
    for (int t = 0; t < TSTEPS; t += 2) {
        body(t,     hreg[0], hreg[1]);
        body(t + 1, hreg[1], hreg[0]);
    }
    body(TSTEPS, hreg[0], hreg[1]);   // drain: layer1 step T-1

    // epilogue: FC on fp32 final h1
    #pragma unroll
    for (int r = 0; r < 2; ++r) uS.hfin[(2 * g + r) * H + u] = h1fin[r];
    __syncthreads();
    if (tid < BT * 2) {
        const int b = tid >> 1, cls = tid & 1;
        float s = bfc[cls];
        for (int k = 0; k < H; ++k) s += uS.hfin[b * H + k] * Wfc[cls * H + k];
        out[(size_t)(bb + b) * 2 + cls] = s;
    }
}

extern "C" void kernel_launch(void* const* d_in, const int* in_sizes, int n_in,
                              void* d_out, int out_size, void* d_ws, size_t ws_size,
                              hipStream_t stream) {
    const float* x    = (const float*)d_in[0];
    const float* Wih0 = (const float*)d_in[1];
    const float* Whh0 = (const float*)d_in[2];
    const float* bih0 = (const float*)d_in[3];
    const float* bhh0 = (const float*)d_in[4];
    const float* Wih1 = (const float*)d_in[5];
    const float* Whh1 = (const float*)d_in[6];
    const float* bih1 = (const float*)d_in[7];
    const float* bhh1 = (const float*)d_in[8];
    const float* Wfc  = (const float*)d_in[9];
    const float* bfc  = (const float*)d_in[10];
    float* out = (float*)d_out;

    lstm2_kernel<<<NBLK, 256, 0, stream>>>(x, Wih0, Whh0, bih0, bhh0,
                                           Wih1, Whh1, bih1, bhh1, Wfc, bfc, out);
}